// Round 7
// baseline (390.336 us; speedup 1.0000x reference)
//
#include <hip/hip_runtime.h>
#include <cstdint>

typedef double d4 __attribute__((ext_vector_type(4)));

// ---------------------------------------------------------------------------
// SNN: 64-step scan over 3 spike-gated linear layers, all internal math f64.
// GEMM uses v_mfma_f64_16x16x4_f64 with an on-device-probed fragment layout
// (round-4 lesson: f64 MFMA layout differs from the bf16 family).
// Round-5 lesson: 1-deep prefetch < HBM latency -> 35% MfmaUtil. Depth-2
// pipeline with 3 SSA register sets fixed it (64%).
// Round-6 lesson: remaining 36% idle = grid geometry (4 blocks/CU quantum,
// 2.9 waves/SIMD). Fix: j-width 16 per wave (4 MFMA/step, 16 AGPR) -> 2x
// waves (6/SIMD), finer interleave, same cover.
// ---------------------------------------------------------------------------

__global__ __launch_bounds__(64) void k_probe(int* __restrict__ lut)
{
    int l = threadIdx.x;
    d4 z = {0.0, 0.0, 0.0, 0.0};
    d4 d1 = __builtin_amdgcn_mfma_f64_16x16x4f64(1.0, (double)l, z, 0, 0, 0);
    d4 d2 = __builtin_amdgcn_mfma_f64_16x16x4f64((double)l, 1.0, z, 0, 0, 0);
    int amode = 0, bmode = 0;
    int rw[4], cl[4];
#pragma unroll
    for (int r = 0; r < 4; ++r) {
        int v1 = (int)(d1[r] + 0.5);
        if ((v1 & 3) == 0) { cl[r] = (v1 - 96) >> 2; bmode = 0; }
        else               { cl[r] = (v1 - 6) >> 4;  bmode = 1; }
        int v2 = (int)(d2[r] + 0.5);
        if ((v2 & 3) == 0) { rw[r] = (v2 - 96) >> 2; amode = 0; }
        else               { rw[r] = (v2 - 6) >> 4;  amode = 1; }
    }
    {
        int m = l >> 2, k = l & 3;
        lut[l] = (amode == 0) ? (m + (k << 4)) : ((m << 2) + k);
    }
    lut[64 + l]  = (bmode == 0) ? (l >> 4) : (l & 3);
    lut[128 + l] = (bmode == 0) ? (l & 15) : (l >> 2);
#pragma unroll
    for (int r = 0; r < 4; ++r) {
        lut[192 + (r << 6) + l] = rw[r];
        lut[448 + (r << 6) + l] = cl[r];
    }
}

// SA block layout: SA[i>>2][tt=t>>4][ lane = lutAinv[(t&15)*4 + (i&3)] ]
__global__ __launch_bounds__(256) void k_input(const float* __restrict__ img,
                                               float* __restrict__ out0, // 65 x n
                                               double* __restrict__ SA0,
                                               const int* __restrict__ lut, int n)
{
    int i = blockIdx.x * 256 + threadIdx.x;
    if (i >= n) return;
    int lanes[16];
#pragma unroll
    for (int m = 0; m < 16; ++m) lanes[m] = lut[(m << 2) + (i & 3)];
    double* base = SA0 + ((size_t)(i >> 2) << 8);
    double m = 0.0;
    double x = (double)img[i];
#pragma unroll
    for (int t = 0; t < 64; ++t) {
        m += x;
        bool fire = (m >= 1.0);
        if (fire) m -= 1.0;          // input layer: no decay
        out0[(size_t)t * n + i] = fire ? 1.0f : 0.0f;
        base[((t >> 4) << 6) + lanes[t & 15]] = fire ? 1.0 : 0.0;
    }
    out0[(size_t)64 * n + i] = 0.0f; // pad_tail: last row zero
}

// MFMA spike-gated GEMM partials: P[c][t][j] = sum_{i in chunk c} S[t][i]*W[i][j]
// Grid: (n_out/64, nchunks). Block 256 = 4 waves; each wave owns 16 j x 64 t.
// Depth-2 software pipeline, 3 SSA register sets; 4 MFMA + 5 loads per step.
__global__ __launch_bounds__(256) void k_gemm(const float* __restrict__ W,
                                              const double* __restrict__ SA,
                                              double* __restrict__ P,
                                              const int* __restrict__ lut,
                                              int n_in, int n_out, int i_per_chunk)
{
    const int lane = threadIdx.x & 63;
    const int wv   = threadIdx.x >> 6;
    const int j0   = blockIdx.x * 64 + wv * 16;
    const int c    = blockIdx.y;

    const int kB = lut[64 + lane];
    const int nB = lut[128 + lane];
    int rw[4], cl[4];
#pragma unroll
    for (int r = 0; r < 4; ++r) {
        rw[r] = lut[192 + (r << 6) + lane];
        cl[r] = lut[448 + (r << 6) + lane];
    }

    int i0 = c * i_per_chunk;
    int i1 = i0 + i_per_chunk; if (i1 > n_in) i1 = n_in;
    int nsteps = (i1 > i0) ? ((i1 - i0) >> 2) : 0;   // 4 i's per step

    d4 acc[4];
#pragma unroll
    for (int tt = 0; tt < 4; ++tt) acc[tt] = (d4){0.0, 0.0, 0.0, 0.0};

    const size_t wstep = (size_t)4 * n_out;          // W elems per step
    const float*  wp0 = W  + (size_t)(i0 + kB) * n_out + j0 + nB;
    const double* ap0 = SA + (((size_t)i0 >> 2) << 8) + lane;

    // three load sets, each serving steps s = k, k+3, k+6, ...
    const float*  Awp = wp0;              const double* Aap = ap0;
    const float*  Bwp = wp0 + wstep;      const double* Bap = ap0 + 256;
    const float*  Cwp = wp0 + 2 * wstep;  const double* Cap = ap0 + 512;
    double Aa0, Aa1, Aa2, Aa3; float Ab0;
    double Ba0, Ba1, Ba2, Ba3; float Bb0;
    double Ca0, Ca1, Ca2, Ca3; float Cb0;

#define LOADSET(S, sidx) do {                                                  \
        if ((sidx) < nsteps) {                                                 \
            S##b0 = S##wp[0];                                                  \
            S##a0 = S##ap[0];  S##a1 = S##ap[64];                              \
            S##a2 = S##ap[128]; S##a3 = S##ap[192];                            \
        } else {                                                               \
            S##b0 = 0.f;                                                       \
            S##a0 = 0.0; S##a1 = 0.0; S##a2 = 0.0; S##a3 = 0.0;                \
        }                                                                      \
        S##wp += 3 * wstep; S##ap += 768;                                      \
    } while (0)

#define COMPUTESET(S) do {                                                     \
        double b0 = (double)S##b0;                                             \
        acc[0] = __builtin_amdgcn_mfma_f64_16x16x4f64(S##a0, b0, acc[0], 0, 0, 0); \
        acc[1] = __builtin_amdgcn_mfma_f64_16x16x4f64(S##a1, b0, acc[1], 0, 0, 0); \
        acc[2] = __builtin_amdgcn_mfma_f64_16x16x4f64(S##a2, b0, acc[2], 0, 0, 0); \
        acc[3] = __builtin_amdgcn_mfma_f64_16x16x4f64(S##a3, b0, acc[3], 0, 0, 0); \
    } while (0)

    LOADSET(A, 0);
    LOADSET(B, 1);
    LOADSET(C, 2);

    int rounds = (nsteps + 2) / 3;
    int s = 0;
    for (int r = 0; r < rounds; ++r) {
        COMPUTESET(A); LOADSET(A, s + 3);   // consumed 2 compute-steps later
        COMPUTESET(B); LOADSET(B, s + 4);
        COMPUTESET(C); LOADSET(C, s + 5);
        s += 3;
    }
#undef LOADSET
#undef COMPUTESET

    // D element (lane, r) sits at (row rw[r], col cl[r]) of its 16x16 tile.
    double* pc = P + (size_t)c * 64 * n_out;
#pragma unroll
    for (int tt = 0; tt < 4; ++tt)
#pragma unroll
        for (int r = 0; r < 4; ++r)
            pc[(size_t)(tt * 16 + rw[r]) * n_out + (j0 + cl[r])] = acc[tt][r];
}

// U[t][j] = sum over chunks c of P[c][t][j]  (fixed order: deterministic)
__global__ __launch_bounds__(256) void k_reduceU(const double* __restrict__ P,
                                                 double* __restrict__ U,
                                                 int nchunks, int n_out)
{
    int gid = blockIdx.x * 256 + threadIdx.x;
    int total = 64 * n_out;
    if (gid >= total) return;
    int t = gid / n_out;
    int j = gid - t * n_out;
    double s = 0.0;
    for (int c = 0; c < nchunks; ++c)
        s += P[((size_t)c * 64 + t) * n_out + j];
    U[gid] = s;
}

// Per-neuron membrane scan; emits next layer's spike fragments via the LUT.
// shift=1 => this layer consumes the previous step's spikes (read U[t-1]).
__global__ __launch_bounds__(256) void k_scan(const double* __restrict__ U,
                                              float* __restrict__ outS, // 65 x n_out (pad_head)
                                              double* __restrict__ SAn, // may be null
                                              const int* __restrict__ lut,
                                              int n_out, int shift)
{
    int j = blockIdx.x * 256 + threadIdx.x;
    if (j >= n_out) return;
    int lanes[16];
#pragma unroll
    for (int m = 0; m < 16; ++m) lanes[m] = lut[(m << 2) + (j & 3)];
    double* base = SAn ? (SAn + ((size_t)(j >> 2) << 8)) : (double*)nullptr;
    double m = 0.0;
    outS[j] = 0.0f;                           // row 0 zero (pad_head)
#pragma unroll
    for (int t = 0; t < 64; ++t) {
        int s = t - shift;
        double u = (s >= 0) ? U[(size_t)s * n_out + j] : 0.0;
        m += u;
        bool fire = (m >= 1.0);
        m = fire ? (m - 1.0) : (m * 0.5);
        outS[(size_t)(t + 1) * n_out + j] = fire ? 1.0f : 0.0f;
        if (base) base[((t >> 4) << 6) + lanes[t & 15]] = fire ? 1.0 : 0.0;
    }
}

extern "C" void kernel_launch(void* const* d_in, const int* in_sizes, int n_in_cnt,
                              void* d_out, int out_size, void* d_ws, size_t ws_size,
                              hipStream_t stream)
{
    const float* img = (const float*)d_in[0];
    const float* w1  = (const float*)d_in[1];
    const float* w2  = (const float*)d_in[2];
    const float* w3  = (const float*)d_in[3];

    const int N0 = 16384, N1 = 4096, N2 = 4096, N3 = 1024;

    float* out0 = (float*)d_out;
    float* out1 = out0 + (size_t)65 * N0;
    float* out2 = out1 + (size_t)65 * N1;
    float* out3 = out2 + (size_t)65 * N2;

    // workspace layout
    char* ws = (char*)d_ws;
    const size_t MB = 1024 * 1024;
    double* SA0 = (double*)(ws);               // 16384*64*8 = 8 MiB
    double* SA1 = (double*)(ws + 8 * MB);      //  2 MiB
    double* SA2 = (double*)(ws + 10 * MB);     //  2 MiB
    double* U   = (double*)(ws + 12 * MB);     //  2 MiB
    int*    lut = (int*)   (ws + 14 * MB);     //  2816 B (704 ints)
    double* P   = (double*)(ws + 14 * MB + 4096);

    size_t fixed = 14 * MB + 4096;
    size_t pbudget = (ws_size > fixed) ? (ws_size - fixed) : 0;

    // P bytes per chunk = 64 t x n_out x 8B = 512*n_out
    auto clampi = [](long v, int lo, int hi) { int x = (int)v; if (x < lo) x = lo; if (x > hi) x = hi; return x; };
    int C1 = clampi((long)(pbudget / (512ull * N1)), 1, 24);
    int C2 = clampi((long)(pbudget / (512ull * N2)), 1, 24);
    int C3 = clampi((long)(pbudget / (512ull * N3)), 1, 48);

    auto ipc4 = [](int n_in, int C) { return (((n_in + C - 1) / C) + 3) & ~3; };

    // measure the f64 MFMA fragment layout (writes lut; same stream -> ordered)
    k_probe<<<1, 64, 0, stream>>>(lut);

    // layer 0 (input): spikes + fragment-layout S0
    k_input<<<N0 / 256, 256, 0, stream>>>(img, out0, SA0, lut, N0);

    // layer 1: U1 = S0 @ W1 (same-step spikes)
    k_gemm<<<dim3(N1 / 64, C1), 256, 0, stream>>>(w1, SA0, P, lut, N0, N1, ipc4(N0, C1));
    k_reduceU<<<(64 * N1) / 256, 256, 0, stream>>>(P, U, C1, N1);
    k_scan<<<N1 / 256, 256, 0, stream>>>(U, out1, SA1, lut, N1, 0);

    // layer 2: uses previous-step s1
    k_gemm<<<dim3(N2 / 64, C2), 256, 0, stream>>>(w2, SA1, P, lut, N1, N2, ipc4(N1, C2));
    k_reduceU<<<(64 * N2) / 256, 256, 0, stream>>>(P, U, C2, N2);
    k_scan<<<N2 / 256, 256, 0, stream>>>(U, out2, SA2, lut, N2, 1);

    // layer 3: uses previous-step s2
    k_gemm<<<dim3(N3 / 64, C3), 256, 0, stream>>>(w3, SA2, P, lut, N1, N3, ipc4(N1, C3));
    k_reduceU<<<(64 * N3) / 256, 256, 0, stream>>>(P, U, C3, N3);
    k_scan<<<N3 / 256, 256, 0, stream>>>(U, out3, (double*)nullptr, lut, N3, 1);
}

// Round 8
// 359.751 us; speedup vs baseline: 1.0850x; 1.0850x over previous
//
#include <hip/hip_runtime.h>
#include <cstdint>

typedef double d4 __attribute__((ext_vector_type(4)));

// ---------------------------------------------------------------------------
// SNN: 64-step scan over 3 spike-gated linear layers, all internal math f64.
// GEMM uses v_mfma_f64_16x16x4_f64 with an on-device-probed fragment layout
// (round-4 lesson: f64 MFMA layout differs from the bf16 family).
// Round-5: depth-2 pipeline (3 SSA register sets) lifted MfmaUtil 35->64%.
// Round-7 lesson: smaller steps + more waves REGRESSED (48%). Utilization
// tracks per-step MFMA:load ratio. Fix: j=64/wave -> 16 MFMA per step vs
// 8 loads (ratio 2.0), 1-wave blocks, 2 waves/SIMD exactly at C=32.
// ---------------------------------------------------------------------------

__global__ __launch_bounds__(64) void k_probe(int* __restrict__ lut)
{
    int l = threadIdx.x;
    d4 z = {0.0, 0.0, 0.0, 0.0};
    d4 d1 = __builtin_amdgcn_mfma_f64_16x16x4f64(1.0, (double)l, z, 0, 0, 0);
    d4 d2 = __builtin_amdgcn_mfma_f64_16x16x4f64((double)l, 1.0, z, 0, 0, 0);
    int amode = 0, bmode = 0;
    int rw[4], cl[4];
#pragma unroll
    for (int r = 0; r < 4; ++r) {
        int v1 = (int)(d1[r] + 0.5);
        if ((v1 & 3) == 0) { cl[r] = (v1 - 96) >> 2; bmode = 0; }
        else               { cl[r] = (v1 - 6) >> 4;  bmode = 1; }
        int v2 = (int)(d2[r] + 0.5);
        if ((v2 & 3) == 0) { rw[r] = (v2 - 96) >> 2; amode = 0; }
        else               { rw[r] = (v2 - 6) >> 4;  amode = 1; }
    }
    {
        int m = l >> 2, k = l & 3;
        lut[l] = (amode == 0) ? (m + (k << 4)) : ((m << 2) + k);
    }
    lut[64 + l]  = (bmode == 0) ? (l >> 4) : (l & 3);
    lut[128 + l] = (bmode == 0) ? (l & 15) : (l >> 2);
#pragma unroll
    for (int r = 0; r < 4; ++r) {
        lut[192 + (r << 6) + l] = rw[r];
        lut[448 + (r << 6) + l] = cl[r];
    }
}

// SA block layout: SA[i>>2][tt=t>>4][ lane = lutAinv[(t&15)*4 + (i&3)] ]
__global__ __launch_bounds__(256) void k_input(const float* __restrict__ img,
                                               float* __restrict__ out0, // 65 x n
                                               double* __restrict__ SA0,
                                               const int* __restrict__ lut, int n)
{
    int i = blockIdx.x * 256 + threadIdx.x;
    if (i >= n) return;
    int lanes[16];
#pragma unroll
    for (int m = 0; m < 16; ++m) lanes[m] = lut[(m << 2) + (i & 3)];
    double* base = SA0 + ((size_t)(i >> 2) << 8);
    double m = 0.0;
    double x = (double)img[i];
#pragma unroll
    for (int t = 0; t < 64; ++t) {
        m += x;
        bool fire = (m >= 1.0);
        if (fire) m -= 1.0;          // input layer: no decay
        out0[(size_t)t * n + i] = fire ? 1.0f : 0.0f;
        base[((t >> 4) << 6) + lanes[t & 15]] = fire ? 1.0 : 0.0;
    }
    out0[(size_t)64 * n + i] = 0.0f; // pad_tail: last row zero
}

// MFMA spike-gated GEMM partials: P[c][t][j] = sum_{i in chunk c} S[t][i]*W[i][j]
// Grid: (n_out/64, nchunks). Block = 1 wave (64 threads); wave owns 64 j x 64 t.
// Depth-2 software pipeline, 3 SSA register sets; 16 MFMA + 8 loads per step.
__global__ __launch_bounds__(64) void k_gemm(const float* __restrict__ W,
                                             const double* __restrict__ SA,
                                             double* __restrict__ P,
                                             const int* __restrict__ lut,
                                             int n_in, int n_out, int i_per_chunk)
{
    const int lane = threadIdx.x & 63;
    const int j0   = blockIdx.x * 64;
    const int c    = blockIdx.y;

    const int kB = lut[64 + lane];
    const int nB = lut[128 + lane];
    int rw[4], cl[4];
#pragma unroll
    for (int r = 0; r < 4; ++r) {
        rw[r] = lut[192 + (r << 6) + lane];
        cl[r] = lut[448 + (r << 6) + lane];
    }

    int i0 = c * i_per_chunk;
    int i1 = i0 + i_per_chunk; if (i1 > n_in) i1 = n_in;
    int nsteps = (i1 > i0) ? ((i1 - i0) >> 2) : 0;   // 4 i's per step

    d4 acc[4][4];   // [jt][tt]
#pragma unroll
    for (int jt = 0; jt < 4; ++jt)
#pragma unroll
        for (int tt = 0; tt < 4; ++tt) acc[jt][tt] = (d4){0.0, 0.0, 0.0, 0.0};

    const size_t wstep = (size_t)4 * n_out;          // W elems per step
    const float*  wp0 = W  + (size_t)(i0 + kB) * n_out + j0 + nB;
    const double* ap0 = SA + (((size_t)i0 >> 2) << 8) + lane;

    // three load sets, each serving steps s = k, k+3, k+6, ...
    const float*  Awp = wp0;              const double* Aap = ap0;
    const float*  Bwp = wp0 + wstep;      const double* Bap = ap0 + 256;
    const float*  Cwp = wp0 + 2 * wstep;  const double* Cap = ap0 + 512;
    double Aa0, Aa1, Aa2, Aa3; float Ab0, Ab1, Ab2, Ab3;
    double Ba0, Ba1, Ba2, Ba3; float Bb0, Bb1, Bb2, Bb3;
    double Ca0, Ca1, Ca2, Ca3; float Cb0, Cb1, Cb2, Cb3;

#define LOADSET(S, sidx) do {                                                  \
        if ((sidx) < nsteps) {                                                 \
            S##b0 = S##wp[0];  S##b1 = S##wp[16];                              \
            S##b2 = S##wp[32]; S##b3 = S##wp[48];                              \
            S##a0 = S##ap[0];  S##a1 = S##ap[64];                              \
            S##a2 = S##ap[128]; S##a3 = S##ap[192];                            \
        } else {                                                               \
            S##b0 = 0.f; S##b1 = 0.f; S##b2 = 0.f; S##b3 = 0.f;                \
            S##a0 = 0.0; S##a1 = 0.0; S##a2 = 0.0; S##a3 = 0.0;                \
        }                                                                      \
        S##wp += 3 * wstep; S##ap += 768;                                      \
    } while (0)

#define COMPUTESET(S) do {                                                     \
        double b;                                                              \
        b = (double)S##b0;                                                     \
        acc[0][0] = __builtin_amdgcn_mfma_f64_16x16x4f64(S##a0, b, acc[0][0], 0, 0, 0); \
        acc[0][1] = __builtin_amdgcn_mfma_f64_16x16x4f64(S##a1, b, acc[0][1], 0, 0, 0); \
        acc[0][2] = __builtin_amdgcn_mfma_f64_16x16x4f64(S##a2, b, acc[0][2], 0, 0, 0); \
        acc[0][3] = __builtin_amdgcn_mfma_f64_16x16x4f64(S##a3, b, acc[0][3], 0, 0, 0); \
        b = (double)S##b1;                                                     \
        acc[1][0] = __builtin_amdgcn_mfma_f64_16x16x4f64(S##a0, b, acc[1][0], 0, 0, 0); \
        acc[1][1] = __builtin_amdgcn_mfma_f64_16x16x4f64(S##a1, b, acc[1][1], 0, 0, 0); \
        acc[1][2] = __builtin_amdgcn_mfma_f64_16x16x4f64(S##a2, b, acc[1][2], 0, 0, 0); \
        acc[1][3] = __builtin_amdgcn_mfma_f64_16x16x4f64(S##a3, b, acc[1][3], 0, 0, 0); \
        b = (double)S##b2;                                                     \
        acc[2][0] = __builtin_amdgcn_mfma_f64_16x16x4f64(S##a0, b, acc[2][0], 0, 0, 0); \
        acc[2][1] = __builtin_amdgcn_mfma_f64_16x16x4f64(S##a1, b, acc[2][1], 0, 0, 0); \
        acc[2][2] = __builtin_amdgcn_mfma_f64_16x16x4f64(S##a2, b, acc[2][2], 0, 0, 0); \
        acc[2][3] = __builtin_amdgcn_mfma_f64_16x16x4f64(S##a3, b, acc[2][3], 0, 0, 0); \
        b = (double)S##b3;                                                     \
        acc[3][0] = __builtin_amdgcn_mfma_f64_16x16x4f64(S##a0, b, acc[3][0], 0, 0, 0); \
        acc[3][1] = __builtin_amdgcn_mfma_f64_16x16x4f64(S##a1, b, acc[3][1], 0, 0, 0); \
        acc[3][2] = __builtin_amdgcn_mfma_f64_16x16x4f64(S##a2, b, acc[3][2], 0, 0, 0); \
        acc[3][3] = __builtin_amdgcn_mfma_f64_16x16x4f64(S##a3, b, acc[3][3], 0, 0, 0); \
    } while (0)

    LOADSET(A, 0);
    LOADSET(B, 1);
    LOADSET(C, 2);

    int rounds = (nsteps + 2) / 3;
    int s = 0;
    for (int r = 0; r < rounds; ++r) {
        COMPUTESET(A); LOADSET(A, s + 3);   // consumed 2 compute-steps later
        COMPUTESET(B); LOADSET(B, s + 4);
        COMPUTESET(C); LOADSET(C, s + 5);
        s += 3;
    }
#undef LOADSET
#undef COMPUTESET

    // D element (lane, r) sits at (row rw[r], col cl[r]) of its 16x16 tile.
    double* pc = P + (size_t)c * 64 * n_out;
#pragma unroll
    for (int jt = 0; jt < 4; ++jt)
#pragma unroll
        for (int tt = 0; tt < 4; ++tt)
#pragma unroll
            for (int r = 0; r < 4; ++r)
                pc[(size_t)(tt * 16 + rw[r]) * n_out + (j0 + jt * 16 + cl[r])] = acc[jt][tt][r];
}

// U[t][j] = sum over chunks c of P[c][t][j]  (fixed order: deterministic)
__global__ __launch_bounds__(256) void k_reduceU(const double* __restrict__ P,
                                                 double* __restrict__ U,
                                                 int nchunks, int n_out)
{
    int gid = blockIdx.x * 256 + threadIdx.x;
    int total = 64 * n_out;
    if (gid >= total) return;
    int t = gid / n_out;
    int j = gid - t * n_out;
    double s = 0.0;
    for (int c = 0; c < nchunks; ++c)
        s += P[((size_t)c * 64 + t) * n_out + j];
    U[gid] = s;
}

// Per-neuron membrane scan; emits next layer's spike fragments via the LUT.
// shift=1 => this layer consumes the previous step's spikes (read U[t-1]).
__global__ __launch_bounds__(256) void k_scan(const double* __restrict__ U,
                                              float* __restrict__ outS, // 65 x n_out (pad_head)
                                              double* __restrict__ SAn, // may be null
                                              const int* __restrict__ lut,
                                              int n_out, int shift)
{
    int j = blockIdx.x * 256 + threadIdx.x;
    if (j >= n_out) return;
    int lanes[16];
#pragma unroll
    for (int m = 0; m < 16; ++m) lanes[m] = lut[(m << 2) + (j & 3)];
    double* base = SAn ? (SAn + ((size_t)(j >> 2) << 8)) : (double*)nullptr;
    double m = 0.0;
    outS[j] = 0.0f;                           // row 0 zero (pad_head)
#pragma unroll
    for (int t = 0; t < 64; ++t) {
        int s = t - shift;
        double u = (s >= 0) ? U[(size_t)s * n_out + j] : 0.0;
        m += u;
        bool fire = (m >= 1.0);
        m = fire ? (m - 1.0) : (m * 0.5);
        outS[(size_t)(t + 1) * n_out + j] = fire ? 1.0f : 0.0f;
        if (base) base[((t >> 4) << 6) + lanes[t & 15]] = fire ? 1.0 : 0.0;
    }
}

extern "C" void kernel_launch(void* const* d_in, const int* in_sizes, int n_in_cnt,
                              void* d_out, int out_size, void* d_ws, size_t ws_size,
                              hipStream_t stream)
{
    const float* img = (const float*)d_in[0];
    const float* w1  = (const float*)d_in[1];
    const float* w2  = (const float*)d_in[2];
    const float* w3  = (const float*)d_in[3];

    const int N0 = 16384, N1 = 4096, N2 = 4096, N3 = 1024;

    float* out0 = (float*)d_out;
    float* out1 = out0 + (size_t)65 * N0;
    float* out2 = out1 + (size_t)65 * N1;
    float* out3 = out2 + (size_t)65 * N2;

    // workspace layout
    char* ws = (char*)d_ws;
    const size_t MB = 1024 * 1024;
    double* SA0 = (double*)(ws);               // 16384*64*8 = 8 MiB
    double* SA1 = (double*)(ws + 8 * MB);      //  2 MiB
    double* SA2 = (double*)(ws + 10 * MB);     //  2 MiB
    double* U   = (double*)(ws + 12 * MB);     //  2 MiB
    int*    lut = (int*)   (ws + 14 * MB);     //  2816 B (704 ints)
    double* P   = (double*)(ws + 14 * MB + 4096);

    size_t fixed = 14 * MB + 4096;
    size_t pbudget = (ws_size > fixed) ? (ws_size - fixed) : 0;

    // P bytes per chunk = 64 t x n_out x 8B = 512*n_out
    auto clampi = [](long v, int lo, int hi) { int x = (int)v; if (x < lo) x = lo; if (x > hi) x = hi; return x; };
    int C1 = clampi((long)(pbudget / (512ull * N1)), 1, 32);  // 2048 blocks @32
    int C2 = clampi((long)(pbudget / (512ull * N2)), 1, 32);
    int C3 = clampi((long)(pbudget / (512ull * N3)), 1, 64);  // 1024 blocks @64

    auto ipc4 = [](int n_in, int C) { return (((n_in + C - 1) / C) + 3) & ~3; };

    // measure the f64 MFMA fragment layout (writes lut; same stream -> ordered)
    k_probe<<<1, 64, 0, stream>>>(lut);

    // layer 0 (input): spikes + fragment-layout S0
    k_input<<<N0 / 256, 256, 0, stream>>>(img, out0, SA0, lut, N0);

    // layer 1: U1 = S0 @ W1 (same-step spikes)
    k_gemm<<<dim3(N1 / 64, C1), 64, 0, stream>>>(w1, SA0, P, lut, N0, N1, ipc4(N0, C1));
    k_reduceU<<<(64 * N1) / 256, 256, 0, stream>>>(P, U, C1, N1);
    k_scan<<<N1 / 256, 256, 0, stream>>>(U, out1, SA1, lut, N1, 0);

    // layer 2: uses previous-step s1
    k_gemm<<<dim3(N2 / 64, C2), 64, 0, stream>>>(w2, SA1, P, lut, N1, N2, ipc4(N1, C2));
    k_reduceU<<<(64 * N2) / 256, 256, 0, stream>>>(P, U, C2, N2);
    k_scan<<<N2 / 256, 256, 0, stream>>>(U, out2, SA2, lut, N2, 1);

    // layer 3: uses previous-step s2
    k_gemm<<<dim3(N3 / 64, C3), 64, 0, stream>>>(w3, SA2, P, lut, N1, N3, ipc4(N1, C3));
    k_reduceU<<<(64 * N3) / 256, 256, 0, stream>>>(P, U, C3, N3);
    k_scan<<<N3 / 256, 256, 0, stream>>>(U, out3, (double*)nullptr, lut, N3, 1);
}